// Round 16
// baseline (134.895 us; speedup 1.0000x reference)
//
#include <hip/hip_runtime.h>
#include <stdint.h>

#define B_    1024
#define FV_   4096
#define E_    256
#define Z_    257
#define NS_   16
#define NSB_  16384
#define EPS_  1e-3f

typedef __attribute__((ext_vector_type(8))) short short8v;
typedef __attribute__((ext_vector_type(4))) float f32x4;
#define MFMA16(a,b,c) __builtin_amdgcn_mfma_f32_16x16x32_bf16(a,b,c,0,0,0)

// LDS-only barrier: waits ds ops, leaves global loads in flight (loop has no
// global writes, so vmcnt drain -- what __syncthreads emits -- is pure waste).
__device__ __forceinline__ void bar_lds(){
  asm volatile("s_waitcnt lgkmcnt(0)\n\ts_barrier" ::: "memory");
}

// ---------------- threefry2x32 (20 rounds) ----------------
__host__ __device__ __forceinline__ uint32_t rotl32(uint32_t v, int r){
  return (v << r) | (v >> (32 - r));
}
__host__ __device__ __forceinline__ void tf2x32(uint32_t k0, uint32_t k1,
    uint32_t x0, uint32_t x1, uint32_t* o0, uint32_t* o1){
  uint32_t ks2 = k0 ^ k1 ^ 0x1BD11BDAu;
  x0 += k0; x1 += k1;
#define TFR(r) { x0 += x1; x1 = rotl32(x1, (r)); x1 ^= x0; }
  TFR(13) TFR(15) TFR(26) TFR(6)
  x0 += k1;  x1 += ks2 + 1u;
  TFR(17) TFR(29) TFR(16) TFR(24)
  x0 += ks2; x1 += k0 + 2u;
  TFR(13) TFR(15) TFR(26) TFR(6)
  x0 += k0;  x1 += k1 + 3u;
  TFR(17) TFR(29) TFR(16) TFR(24)
  x0 += k1;  x1 += ks2 + 4u;
  TFR(13) TFR(15) TFR(26) TFR(6)
  x0 += ks2; x1 += k0 + 5u;
#undef TFR
  *o0 = x0; *o1 = x1;
}
__device__ __forceinline__ uint64_t tf64(uint32_t k0, uint32_t k1, uint32_t c){
  uint32_t a, b; tf2x32(k0, k1, 0u, c, &a, &b);
  return ((uint64_t)b << 32) | (uint64_t)a;
}
__device__ __forceinline__ float u01(uint32_t bits){
  return __uint_as_float((bits >> 9) | 0x3f800000u) - 1.0f;
}
__device__ __forceinline__ float logsigf(float x){
  return fminf(x, 0.f) - __logf(1.f + __expf(-fabsf(x)));
}
__device__ __forceinline__ float sigf(float x){ return 1.f / (1.f + __expf(-x)); }
__device__ __forceinline__ unsigned short f2bf(float f){
  uint32_t b = __float_as_uint(f);
  return (unsigned short)((b + 0x7fffu + ((b >> 16) & 1u)) >> 16);
}
__device__ __forceinline__ float bf2f(unsigned short u){
  return __uint_as_float(((uint32_t)u) << 16);
}

// ---------------- merged prep kernel ----------------
__global__ __launch_bounds__(256) void k_prep(
    const float* __restrict__ img, const float* __restrict__ wb,
    unsigned short* __restrict__ imgb, float* __restrict__ r2,
    const float* __restrict__ W, unsigned short* __restrict__ Wt,
    const float* __restrict__ whz, unsigned short* __restrict__ whzPh,
    unsigned short* __restrict__ whzTPh){
  __shared__ float ld[32][33];
  __shared__ float red[256];
  int bid = blockIdx.x, t = threadIdx.x;
  if (bid < 1024){
    int b = bid;
    float s = 0.f;
#pragma unroll
    for (int i = 0; i < 4; i++){
      int col = t * 4 + i * 1024;
      float4 v = *(const float4*)&img[(size_t)b * FV_ + col];
      float4 wv = *(const float4*)&wb[col];
      float d0 = v.x - wv.x, d1 = v.y - wv.y, d2 = v.z - wv.z, d3 = v.w - wv.w;
      s = fmaf(d0, d0, fmaf(d1, d1, fmaf(d2, d2, fmaf(d3, d3, s))));
      ushort4 o; o.x = f2bf(d0); o.y = f2bf(d1); o.z = f2bf(d2); o.w = f2bf(d3);
      *(ushort4*)&imgb[(size_t)b * FV_ + col] = o;
    }
    red[t] = s; __syncthreads();
    for (int w = 128; w > 0; w >>= 1){ if (t < w) red[t] += red[t + w]; __syncthreads(); }
    if (!t) r2[b] = red[0];
  } else if (bid < 2048){
    int idx = bid - 1024;
    int f0 = (idx & 127) * 32, e0 = (idx >> 7) * 32;
    int tx = t & 31, ty = t >> 5;
#pragma unroll
    for (int sub = 0; sub < 4; sub++){
      int r = ty + 8 * sub;
      ld[r][tx] = W[(size_t)(f0 + r) * 256 + e0 + tx];
    }
    __syncthreads();
#pragma unroll
    for (int sub = 0; sub < 4; sub++){
      int r = ty + 8 * sub;
      Wt[(size_t)(e0 + r) * 4096 + f0 + tx] = f2bf(ld[tx][r]);
    }
  } else {
    int r = bid - 2048;   // 0..271
    if (r < 256){
      for (int z = t; z < 288; z += 256)
        whzPh[(size_t)r * 288 + z] = (z < Z_) ? f2bf(whz[(size_t)r * Z_ + z]) : (unsigned short)0;
    }
    whzTPh[(size_t)r * 256 + t] = (r < Z_) ? f2bf(whz[(size_t)t * Z_ + r]) : (unsigned short)0;
  }
}

// ---------------- merged setup GEMMs (ata | pp) ----------------
__global__ __launch_bounds__(256) void k_gemms(const unsigned short* __restrict__ Wt,
    const unsigned short* __restrict__ imgb,
    float* __restrict__ ataPart, float* __restrict__ ppPart){
  int bid = blockIdx.x;
  int t = threadIdx.x, lane = t & 63, w = t >> 6, l15 = lane & 15, l4 = lane >> 4;
  if (bid < 256){
    int m0 = (bid & 15) * 16;
    size_t kc = (size_t)(bid >> 4) * 256;
    f32x4 acc[4];
#pragma unroll
    for (int q = 0; q < 4; q++) acc[q] = (f32x4){0.f, 0.f, 0.f, 0.f};
    for (int kt = 0; kt < 8; kt++){
      short8v a = *(const short8v*)&Wt[(size_t)(m0 + l15) * 4096 + kc + kt * 32 + l4 * 8];
#pragma unroll
      for (int q = 0; q < 4; q++){
        short8v b = *(const short8v*)&Wt[(size_t)(w * 64 + q * 16 + l15) * 4096 + kc + kt * 32 + l4 * 8];
        acc[q] = MFMA16(a, b, acc[q]);
      }
    }
    float* dst = ataPart + (size_t)(bid >> 4) * 65536;
#pragma unroll
    for (int q = 0; q < 4; q++)
#pragma unroll
      for (int j = 0; j < 4; j++)
        dst[(size_t)(m0 + l4 * 4 + j) * 256 + w * 64 + q * 16 + l15] = acc[q][j];
  } else {
    int idx = bid - 256;
    int m0 = (idx & 31) * 32;
    size_t kc = (size_t)(idx >> 5) * 512;
    f32x4 acc0[4], acc1[4];
#pragma unroll
    for (int q = 0; q < 4; q++){ acc0[q] = (f32x4){0.f,0.f,0.f,0.f}; acc1[q] = (f32x4){0.f,0.f,0.f,0.f}; }
    for (int kt = 0; kt < 16; kt++){
      short8v a0 = *(const short8v*)&imgb[(size_t)(m0 + l15) * 4096 + kc + kt * 32 + l4 * 8];
      short8v a1 = *(const short8v*)&imgb[(size_t)(m0 + 16 + l15) * 4096 + kc + kt * 32 + l4 * 8];
#pragma unroll
      for (int q = 0; q < 4; q++){
        short8v b = *(const short8v*)&Wt[(size_t)(w * 64 + q * 16 + l15) * 4096 + kc + kt * 32 + l4 * 8];
        acc0[q] = MFMA16(a0, b, acc0[q]);
        acc1[q] = MFMA16(a1, b, acc1[q]);
      }
    }
    float* dst = ppPart + (size_t)(idx >> 5) * (B_ * 256);
#pragma unroll
    for (int q = 0; q < 4; q++)
#pragma unroll
      for (int j = 0; j < 4; j++){
        dst[(size_t)(m0 + l4 * 4 + j) * 256 + w * 64 + q * 16 + l15] = acc0[q][j];
        dst[(size_t)(m0 + 16 + l4 * 4 + j) * 256 + w * 64 + q * 16 + l15] = acc1[q][j];
      }
  }
}

// ---------------- merged reductions ----------------
__global__ void k_reduce(const float* __restrict__ ataPart, unsigned short* __restrict__ Gh,
                         const float* __restrict__ ppPart, float* __restrict__ Pp){
  int bid = blockIdx.x, t = threadIdx.x;
  if (bid < 256){
    int i = bid * 256 + t;
    float s = 0.f;
#pragma unroll
    for (int p = 0; p < 16; p++) s += ataPart[(size_t)p * 65536 + i];
    Gh[i] = f2bf(s);
  } else {
    int i = (bid - 256) * 256 + t;
    float s = 0.f;
#pragma unroll
    for (int p = 0; p < 8; p++) s += ppPart[(size_t)p * (B_ * 256) + i];
    Pp[i] = s;
  }
}

// ---------------- fused 8-step inner loop (r15 + LDS-only barriers, B before S1) ----------------
__global__ __launch_bounds__(512, 1) void k_inner(
    const unsigned short* __restrict__ whzPh,   // [256][288]
    const unsigned short* __restrict__ whzTPh,  // [272][256]
    const unsigned short* __restrict__ Gh,      // [256][256]
    const float* __restrict__ whzb,
    const float* __restrict__ blp,
    const float* __restrict__ Pp,
    const float* __restrict__ bso,
    float* __restrict__ nzOut, float* __restrict__ cA, float* __restrict__ rowB,
    uint32_t hk00, uint32_t hk01, uint32_t hk10, uint32_t hk11,
    uint32_t zk00, uint32_t zk01, uint32_t zk10, uint32_t zk11)
{
  __shared__ unsigned short zb[16][296];
  __shared__ unsigned short hbuf[2][16][296];
  __shared__ unsigned short sgb[16][296];
  __shared__ float zl[16][260];
  __shared__ float ppl[16][256];
  __shared__ float lsb[272];
  __shared__ float xbl[272];
  __shared__ float w256l[256];
  __shared__ uint64_t hbitL[272][2];
  __shared__ uint64_t zbitL[272][2];

  const int t = threadIdx.x;
  const int lane = t & 63;
  const int w = t >> 6;
  const int l15 = lane & 15;
  const int l4 = lane >> 4;
  const int blk = blockIdx.x;
  const int b0 = blk * 16;
  const int n0 = w * 32 + l15;
  const int n1 = n0 + 16;

  const unsigned short epsb = f2bf(EPS_);
  for (int i = t; i < 16 * 296; i += 512){
    int r = i / 296, c = i % 296;
    zb[r][c] = (c < Z_) ? epsb : (unsigned short)0;
    hbuf[0][r][c] = (c < 256) ? epsb : (unsigned short)0;
    hbuf[1][r][c] = 0;
    sgb[r][c] = 0;
  }
  for (int i = t; i < 16 * 260; i += 512){
    int r = i / 260, c = i % 260;
    zl[r][c] = (c < Z_) ? EPS_ : 0.f;
  }
  for (int i = t; i < 4096; i += 512)
    ppl[i >> 8][i & 255] = Pp[(size_t)(b0 + (i >> 8)) * 256 + (i & 255)];
  if (t < 272){
    float x = (t < Z_) ? blp[t] : 0.f;
    xbl[t] = x;
    lsb[t] = logsigf(x);
    hbitL[t][0] = tf64(hk00, hk01, (uint32_t)(blk * 272 + t));
    hbitL[t][1] = tf64(hk10, hk11, (uint32_t)(blk * 272 + t));
    zbitL[t][0] = tf64(zk00, zk01, (uint32_t)(blk * 272 + t));
    zbitL[t][1] = tf64(zk10, zk11, (uint32_t)(blk * 272 + t));
  }
  if (t < 256) w256l[t] = bf2f(whzTPh[(size_t)256 * 256 + t]);

  const unsigned short* wApt0 = &whzPh[(size_t)n0 * 288 + l4 * 8];
  const unsigned short* wApt1 = &whzPh[(size_t)n1 * 288 + l4 * 8];
  const unsigned short* wBpt0 = &Gh[(size_t)n0 * 256 + l4 * 8];
  const unsigned short* wBpt1 = &Gh[(size_t)n1 * 256 + l4 * 8];
  const unsigned short* wCpt0 = &whzTPh[(size_t)n0 * 256 + l4 * 8];
  const unsigned short* wCpt1 = &whzTPh[(size_t)n1 * 256 + l4 * 8];
  const float w256A0 = bf2f(whzPh[(size_t)n0 * 288 + 256]);
  const float w256A1 = bf2f(whzPh[(size_t)n1 * 288 + 256]);
  const float op = __expf(2.f * bso[0]);
  const float wbr0 = whzb[n0], wbr1 = whzb[n1];
  const float lsr0 = logsigf(blp[n0]), lsr1 = logsigf(blp[n1]);
  const float lsr2 = logsigf(blp[256]);
  float hreg0[4] = {EPS_, EPS_, EPS_, EPS_};
  float hreg1[4] = {EPS_, EPS_, EPS_, EPS_};
  __syncthreads();

  for (int s = 0; s < 8; s++){
    const int sg = s >> 2, sh = (s & 3) << 4;
    const int cur = s & 1, nx = cur ^ 1;

    // ---- phase A (needs zb from prev S2) ----
    f32x4 aA0 = {0.f, 0.f, 0.f, 0.f};
    {
      short8v wt[8];
#pragma unroll
      for (int kt = 0; kt < 8; kt++) wt[kt] = *(const short8v*)(wApt0 + kt * 32);
#pragma unroll
      for (int kt = 0; kt < 8; kt++)
        aA0 = MFMA16(*(const short8v*)&zb[l15][kt * 32 + l4 * 8], wt[kt], aA0);
    }
    f32x4 aA1 = {0.f, 0.f, 0.f, 0.f};
    {
      short8v wt[8];
#pragma unroll
      for (int kt = 0; kt < 8; kt++) wt[kt] = *(const short8v*)(wApt1 + kt * 32);
#pragma unroll
      for (int kt = 0; kt < 8; kt++)
        aA1 = MFMA16(*(const short8v*)&zb[l15][kt * 32 + l4 * 8], wt[kt], aA1);
    }
    float d2r0[4], d2r1[4];
#pragma unroll
    for (int j = 0; j < 4; j++){
      int m = l4 * 4 + j;
      float z256v = bf2f(zb[m][256]);
      float hpl0 = aA0[j] + wbr0 + z256v * w256A0;
      float hpl1 = aA1[j] + wbr1 + z256v * w256A1;
      d2r0[j] = logsigf(hpl0);
      d2r1[j] = logsigf(hpl1);
      sgb[m][n0] = f2bf(hreg0[j] * sigf(-hpl0));
      sgb[m][n1] = f2bf(hreg1[j] * sigf(-hpl1));
    }

    // ---- phase B BEFORE S1 (reads hbuf[cur] from prev step; sgb-independent) ----
    f32x4 aB0 = {0.f, 0.f, 0.f, 0.f};
    {
      short8v wt[8];
#pragma unroll
      for (int kt = 0; kt < 8; kt++) wt[kt] = *(const short8v*)(wBpt0 + kt * 32);
#pragma unroll
      for (int kt = 0; kt < 8; kt++)
        aB0 = MFMA16(*(const short8v*)&hbuf[cur][l15][kt * 32 + l4 * 8], wt[kt], aB0);
    }
    f32x4 aB1 = {0.f, 0.f, 0.f, 0.f};
    {
      short8v wt[8];
#pragma unroll
      for (int kt = 0; kt < 8; kt++) wt[kt] = *(const short8v*)(wBpt1 + kt * 32);
#pragma unroll
      for (int kt = 0; kt < 8; kt++)
        aB1 = MFMA16(*(const short8v*)&hbuf[cur][l15][kt * 32 + l4 * 8], wt[kt], aB1);
    }
    bar_lds();   // S1: sgb visible (LDS only; weight loads stay in flight)

    // ---- phase C ----
    f32x4 aC0 = {0.f, 0.f, 0.f, 0.f};
    {
      short8v wt[8];
#pragma unroll
      for (int kt = 0; kt < 8; kt++) wt[kt] = *(const short8v*)(wCpt0 + kt * 32);
#pragma unroll
      for (int kt = 0; kt < 8; kt++)
        aC0 = MFMA16(*(const short8v*)&sgb[l15][kt * 32 + l4 * 8], wt[kt], aC0);
    }
    f32x4 aC1 = {0.f, 0.f, 0.f, 0.f};
    {
      short8v wt[8];
#pragma unroll
      for (int kt = 0; kt < 8; kt++) wt[kt] = *(const short8v*)(wCpt1 + kt * 32);
#pragma unroll
      for (int kt = 0; kt < 8; kt++)
        aC1 = MFMA16(*(const short8v*)&sgb[l15][kt * 32 + l4 * 8], wt[kt], aC1);
    }
    float zdot = 0.f;
    if (w == 0){
      int r = lane & 15, kg = lane >> 4;
#pragma unroll
      for (int c = 0; c < 8; c++){
        short8v sv = *(const short8v*)&sgb[r][kg * 64 + c * 8];
#pragma unroll
        for (int i = 0; i < 8; i++)
          zdot = fmaf(bf2f((unsigned short)sv[i]), w256l[kg * 64 + c * 8 + i], zdot);
      }
      zdot += __shfl_xor(zdot, 16);
      zdot += __shfl_xor(zdot, 32);
    }

    {
      uint64_t hb0w = hbitL[n0][sg], hb1w = hbitL[n1][sg];
#pragma unroll
      for (int j = 0; j < 4; j++){
        int m = l4 * 4 + j;
        float hn0 = sigf(op * (ppl[m][n0] - aB0[j]) + d2r0[j]);
        float hn1 = sigf(op * (ppl[m][n1] - aB1[j]) + d2r1[j]);
        if ((hb0w >> (sh | m)) & 1ull) hreg0[j] = 0.5f * (hreg0[j] + hn0);
        if ((hb1w >> (sh | m)) & 1ull) hreg1[j] = 0.5f * (hreg1[j] + hn1);
        hbuf[nx][m][n0] = f2bf(hreg0[j]);
        hbuf[nx][m][n1] = f2bf(hreg1[j]);
      }
    }
    {
      uint64_t zb0w = zbitL[n0][sg], zb1w = zbitL[n1][sg];
#pragma unroll
      for (int j = 0; j < 4; j++){
        int m = l4 * 4 + j;
        float zx0 = sigf(aC0[j] + lsr0);
        float old0 = zl[m][n0];
        float nz0 = ((zb0w >> (sh | m)) & 1ull) ? 0.5f * (old0 + zx0) : old0;
        zl[m][n0] = nz0; zb[m][n0] = f2bf(nz0);
        float zx1 = sigf(aC1[j] + lsr1);
        float old1 = zl[m][n1];
        float nz1 = ((zb1w >> (sh | m)) & 1ull) ? 0.5f * (old1 + zx1) : old1;
        zl[m][n1] = nz1; zb[m][n1] = f2bf(nz1);
      }
    }
    if (w == 0 && lane < 16){
      int r = lane;
      uint64_t zw = zbitL[256][sg];
      float zx = sigf(zdot + lsr2);
      float old = zl[r][256];
      float nz = ((zw >> (sh | r)) & 1ull) ? 0.5f * (old + zx) : old;
      zl[r][256] = nz; zb[r][256] = f2bf(nz);
    }
    bar_lds();   // S2: zb/hbuf[nx]/zl visible
  }

  {
    int r = t >> 5, g = t & 31;
    float s = 0.f;
    for (int c = g; c < Z_; c += 32){
      float pz = zl[r][c];
      float lgp = __logf(pz);
      float lgq = log1pf(-pz);
      float x = xbl[c];
      nzOut[(size_t)(b0 + r) * Z_ + c] = pz;
      cA[(size_t)(b0 + r) * Z_ + c] = x - lgp + lgq;
      s += -(x - lsb[c]) - lgq;
    }
#pragma unroll
    for (int m = 16; m >= 1; m >>= 1) s += __shfl_xor(s, m);
    if (g == 0) rowB[b0 + r] = s;
  }
}

// ---------------- fused phase 2 (r15 verbatim) ----------------
__global__ __launch_bounds__(256) void k_phase2(
    const float* __restrict__ nzF, const float* __restrict__ cA,
    const float* __restrict__ rowBg,
    const unsigned short* __restrict__ whzPh, const float* __restrict__ whzb,
    const unsigned short* __restrict__ Gh, const float* __restrict__ Pp,
    const float* __restrict__ r2, const float* __restrict__ bso,
    float* __restrict__ joint,
    uint32_t zk0, uint32_t zk1, uint32_t hk0, uint32_t hk1){
  __shared__ unsigned short znl[16][296];
  __shared__ unsigned short hnl[16][264];
  __shared__ float lpl[16];
  __shared__ float sred[4][16][2];

  const int t = threadIdx.x, lane = t & 63, w = t >> 6;
  const int l15 = lane & 15, l4 = lane >> 4;
  const int m0 = blockIdx.x * 16;
  const int bb0 = m0 & (B_ - 1);

  for (int i = t; i < 16 * 32; i += 256)
    znl[i >> 5][256 + (i & 31)] = 0;

  {
    int rl = t >> 4, i = t & 15;
    int rg = m0 + rl;
    int b = bb0 + rl;
    float acc = 0.f;
#pragma unroll
    for (int k = 0; k < 8; k++){
      int tpos = i + 16 * k;
      uint32_t o0, o1;
      tf2x32(zk0, zk1, 0u, (uint32_t)(rg * 130 + tpos), &o0, &o1);
      int z0 = 2 * tpos;
      float pz0 = nzF[(size_t)b * Z_ + z0];
      float pz1 = nzF[(size_t)b * Z_ + z0 + 1];
      int v0 = u01(o0) < pz0;
      int v1 = u01(o1) < pz1;
      uint32_t pack = (v0 ? 0x3F80u : 0u) | (v1 ? 0x3F800000u : 0u);
      *(uint32_t*)&znl[rl][z0] = pack;
      if (v0) acc += cA[(size_t)b * Z_ + z0];
      if (v1) acc += cA[(size_t)b * Z_ + z0 + 1];
    }
#pragma unroll
    for (int msk = 1; msk < 16; msk <<= 1) acc += __shfl_xor(acc, msk);
    if (i == 0){
      uint32_t p0, p1;
      tf2x32(zk0, zk1, 0u, (uint32_t)(rg * 130 + 128), &p0, &p1);
      float pz = nzF[(size_t)b * Z_ + 256];
      int v = u01(p0) < pz;
      znl[rl][256] = v ? (unsigned short)0x3F80 : (unsigned short)0;
      if (v) acc += cA[(size_t)b * Z_ + 256];
      lpl[rl] = rowBg[b] + acc;
    }
  }
  __syncthreads();

  {
    short8v af[9];
#pragma unroll
    for (int kt = 0; kt < 9; kt++)
      af[kt] = *(const short8v*)&znl[l15][kt * 32 + l4 * 8];
#pragma unroll
    for (int q = 0; q < 4; q++){
      int n = w * 64 + q * 16 + l15;
      f32x4 acc = {0.f,0.f,0.f,0.f};
#pragma unroll
      for (int kt = 0; kt < 9; kt++){
        short8v bfr = *(const short8v*)&whzPh[(size_t)n * 288 + kt * 32 + l4 * 8];
        acc = MFMA16(af[kt], bfr, acc);
      }
      float wbv = whzb[n];
      int rbl = l4 * 4;
      int rbg = m0 + rbl;
      uint32_t c0 = (uint32_t)((rbg >> 1) * 256 + n);
      uint32_t ra0, rb0, ra1, rb1;
      tf2x32(hk0, hk1, 0u, c0, &ra0, &rb0);
      tf2x32(hk0, hk1, 0u, c0 + 256, &ra1, &rb1);
      float u[4] = {u01(ra0), u01(rb0), u01(ra1), u01(rb1)};
#pragma unroll
      for (int j = 0; j < 4; j++){
        float pr = sigf(acc[j] + wbv);
        hnl[rbl + j][n] = (u[j] < pr) ? (unsigned short)0x3F80 : (unsigned short)0;
      }
    }
  }
  __syncthreads();

  {
    short8v af[8];
#pragma unroll
    for (int kt = 0; kt < 8; kt++)
      af[kt] = *(const short8v*)&hnl[l15][kt * 32 + l4 * 8];
    float s1[4]={0.f,0.f,0.f,0.f}, s2[4]={0.f,0.f,0.f,0.f};
#pragma unroll
    for (int q = 0; q < 4; q++){
      int n = w * 64 + q * 16 + l15;
      f32x4 acc = {0.f,0.f,0.f,0.f};
#pragma unroll
      for (int kt = 0; kt < 8; kt++){
        short8v bfr = *(const short8v*)&Gh[(size_t)n * 256 + kt * 32 + l4 * 8];
        acc = MFMA16(af[kt], bfr, acc);
      }
#pragma unroll
      for (int j = 0; j < 4; j++){
        int gl = l4 * 4 + j;
        float hv = bf2f(hnl[gl][n]);
        float pp = Pp[(size_t)((m0 + gl) & (B_ - 1)) * 256 + n];
        s1[j] = fmaf(hv, acc[j], s1[j]);
        s2[j] = fmaf(hv, pp, s2[j]);
      }
    }
#pragma unroll
    for (int j = 0; j < 4; j++){
#pragma unroll
      for (int msk = 1; msk < 16; msk <<= 1){
        s1[j] += __shfl_xor(s1[j], msk);
        s2[j] += __shfl_xor(s2[j], msk);
      }
    }
    if (l15 == 0){
#pragma unroll
      for (int j = 0; j < 4; j++){
        sred[w][l4 * 4 + j][0] = s1[j];
        sred[w][l4 * 4 + j][1] = s2[j];
      }
    }
    __syncthreads();
    if (t < 16){
      float S1 = 0.f, S2 = 0.f;
#pragma unroll
      for (int wv = 0; wv < 4; wv++){ S1 += sred[wv][t][0]; S2 += sred[wv][t][1]; }
      int gm = m0 + t;
      int b = gm & (B_ - 1);
      float bs = bso[0];
      float isc2 = __expf(-2.f * bs);
      float se = r2[b] - 2.f * S2 + S1;
      joint[gm] = lpl[t] - 0.5f * isc2 * se - (float)FV_ * (bs + 0.91893853320467274f);
    }
  }
}

__global__ __launch_bounds__(1024) void k_final(const float* __restrict__ joint, float* __restrict__ out){
  int b = threadIdx.x;
  float mx = -3.0e38f;
  for (int n = 0; n < NS_; n++) mx = fmaxf(mx, joint[(size_t)n * B_ + b]);
  float s = 0.f;
  for (int n = 0; n < NS_; n++) s += __expf(joint[(size_t)n * B_ + b] - mx);
  float lse = mx + __logf(s) - 2.772588722239781f;
  __shared__ float red[1024];
  red[b] = lse; __syncthreads();
  for (int w = 512; w > 0; w >>= 1){ if (b < w) red[b] += red[b + w]; __syncthreads(); }
  if (!b) out[0] = -red[0] / (float)B_;
}

// ---------------- host ----------------
extern "C" void kernel_launch(void* const* d_in, const int* in_sizes, int n_in,
                              void* d_out, int out_size, void* d_ws, size_t ws_size,
                              hipStream_t stream){
  const float* img  = (const float*)d_in[0];
  const float* W    = (const float*)d_in[2];
  const float* wb   = (const float*)d_in[3];
  const float* whz  = (const float*)d_in[4];
  const float* whzb = (const float*)d_in[5];
  const float* blp  = (const float*)d_in[6];
  const float* bso  = (const float*)d_in[7];
  float* out = (float*)d_out;
  float* ws = (float*)d_ws;
  (void)in_sizes; (void)n_in; (void)out_size; (void)ws_size;

  size_t off = 0;
  auto nxt = [&](size_t n){ size_t o = off; off += (n + 63) & ~(size_t)63; return o; };
  float* Pp    = ws + nxt((size_t)B_ * 256);
  float* r2    = ws + nxt(B_);
  float* joint = ws + nxt(NSB_);
  float* nzF   = ws + nxt((size_t)B_ * Z_);
  float* cA    = ws + nxt((size_t)B_ * Z_);
  float* rowB  = ws + nxt(B_);
  unsigned short* Gh     = (unsigned short*)(ws + nxt((size_t)256 * 256 / 2));
  unsigned short* whzPh  = (unsigned short*)(ws + nxt((size_t)256 * 288 / 2));
  unsigned short* whzTPh = (unsigned short*)(ws + nxt((size_t)272 * 256 / 2));
  unsigned short* Wt     = (unsigned short*)(ws + nxt((size_t)256 * 4096 / 2));
  unsigned short* imgb   = (unsigned short*)(ws + nxt((size_t)B_ * FV_ / 2));
  float* ataPart = ws + nxt((size_t)16 * 65536);
  float* ppPart  = ws + nxt((size_t)8 * B_ * 256);

  uint32_t hk00, hk01, hk10, hk11, zk00, zk01, zk10, zk11;
  tf2x32(0u, 42u, 1u, 0u, &hk00, &hk01);
  tf2x32(0u, 42u, 1u, 1u, &hk10, &hk11);
  tf2x32(0u, 42u, 2u, 0u, &zk00, &zk01);
  tf2x32(0u, 42u, 2u, 1u, &zk10, &zk11);
  uint32_t sk00, sk01, sk10, sk11;
  tf2x32(0u, 7u, 0u, 0u, &sk00, &sk01);
  tf2x32(0u, 7u, 0u, 1u, &sk10, &sk11);

  k_prep<<<dim3(2320), 256, 0, stream>>>(img, wb, imgb, r2, W, Wt, whz, whzPh, whzTPh);
  k_gemms<<<dim3(512), 256, 0, stream>>>(Wt, imgb, ataPart, ppPart);
  k_reduce<<<dim3(1280), 256, 0, stream>>>(ataPart, Gh, ppPart, Pp);
  k_inner<<<dim3(64), 512, 0, stream>>>(whzPh, whzTPh, Gh, whzb, blp, Pp, bso,
                                        nzF, cA, rowB,
                                        hk00, hk01, hk10, hk11, zk00, zk01, zk10, zk11);
  k_phase2<<<dim3(1024), 256, 0, stream>>>(nzF, cA, rowB, whzPh, whzb, Gh, Pp, r2, bso,
                                           joint, sk00, sk01, sk10, sk11);
  k_final<<<dim3(1), 1024, 0, stream>>>(joint, out);
}

// Round 17
// 123.243 us; speedup vs baseline: 1.0946x; 1.0946x over previous
//
#include <hip/hip_runtime.h>
#include <stdint.h>

#define B_    1024
#define FV_   4096
#define E_    256
#define Z_    257
#define NS_   16
#define NSB_  16384
#define EPS_  1e-3f

typedef __attribute__((ext_vector_type(8))) short short8v;
typedef __attribute__((ext_vector_type(4))) float f32x4;
#define MFMA16(a,b,c) __builtin_amdgcn_mfma_f32_16x16x32_bf16(a,b,c,0,0,0)

// ---------------- threefry2x32 (20 rounds) ----------------
__host__ __device__ __forceinline__ uint32_t rotl32(uint32_t v, int r){
  return (v << r) | (v >> (32 - r));
}
__host__ __device__ __forceinline__ void tf2x32(uint32_t k0, uint32_t k1,
    uint32_t x0, uint32_t x1, uint32_t* o0, uint32_t* o1){
  uint32_t ks2 = k0 ^ k1 ^ 0x1BD11BDAu;
  x0 += k0; x1 += k1;
#define TFR(r) { x0 += x1; x1 = rotl32(x1, (r)); x1 ^= x0; }
  TFR(13) TFR(15) TFR(26) TFR(6)
  x0 += k1;  x1 += ks2 + 1u;
  TFR(17) TFR(29) TFR(16) TFR(24)
  x0 += ks2; x1 += k0 + 2u;
  TFR(13) TFR(15) TFR(26) TFR(6)
  x0 += k0;  x1 += k1 + 3u;
  TFR(17) TFR(29) TFR(16) TFR(24)
  x0 += k1;  x1 += ks2 + 4u;
  TFR(13) TFR(15) TFR(26) TFR(6)
  x0 += ks2; x1 += k0 + 5u;
#undef TFR
  *o0 = x0; *o1 = x1;
}
__device__ __forceinline__ uint64_t tf64(uint32_t k0, uint32_t k1, uint32_t c){
  uint32_t a, b; tf2x32(k0, k1, 0u, c, &a, &b);
  return ((uint64_t)b << 32) | (uint64_t)a;
}
__device__ __forceinline__ float u01(uint32_t bits){
  return __uint_as_float((bits >> 9) | 0x3f800000u) - 1.0f;
}
__device__ __forceinline__ float logsigf(float x){
  return fminf(x, 0.f) - __logf(1.f + __expf(-fabsf(x)));
}
__device__ __forceinline__ float sigf(float x){ return 1.f / (1.f + __expf(-x)); }
__device__ __forceinline__ unsigned short f2bf(float f){
  uint32_t b = __float_as_uint(f);
  return (unsigned short)((b + 0x7fffu + ((b >> 16) & 1u)) >> 16);
}
__device__ __forceinline__ float bf2f(unsigned short u){
  return __uint_as_float(((uint32_t)u) << 16);
}

// ---------------- merged prep kernel ----------------
__global__ __launch_bounds__(256) void k_prep(
    const float* __restrict__ img, const float* __restrict__ wb,
    unsigned short* __restrict__ imgb, float* __restrict__ r2,
    const float* __restrict__ W, unsigned short* __restrict__ Wt,
    const float* __restrict__ whz, unsigned short* __restrict__ whzPh,
    unsigned short* __restrict__ whzTPh){
  __shared__ float ld[32][33];
  __shared__ float red[256];
  int bid = blockIdx.x, t = threadIdx.x;
  if (bid < 1024){
    int b = bid;
    float s = 0.f;
#pragma unroll
    for (int i = 0; i < 4; i++){
      int col = t * 4 + i * 1024;
      float4 v = *(const float4*)&img[(size_t)b * FV_ + col];
      float4 wv = *(const float4*)&wb[col];
      float d0 = v.x - wv.x, d1 = v.y - wv.y, d2 = v.z - wv.z, d3 = v.w - wv.w;
      s = fmaf(d0, d0, fmaf(d1, d1, fmaf(d2, d2, fmaf(d3, d3, s))));
      ushort4 o; o.x = f2bf(d0); o.y = f2bf(d1); o.z = f2bf(d2); o.w = f2bf(d3);
      *(ushort4*)&imgb[(size_t)b * FV_ + col] = o;
    }
    red[t] = s; __syncthreads();
    for (int w = 128; w > 0; w >>= 1){ if (t < w) red[t] += red[t + w]; __syncthreads(); }
    if (!t) r2[b] = red[0];
  } else if (bid < 2048){
    int idx = bid - 1024;
    int f0 = (idx & 127) * 32, e0 = (idx >> 7) * 32;
    int tx = t & 31, ty = t >> 5;
#pragma unroll
    for (int sub = 0; sub < 4; sub++){
      int r = ty + 8 * sub;
      ld[r][tx] = W[(size_t)(f0 + r) * 256 + e0 + tx];
    }
    __syncthreads();
#pragma unroll
    for (int sub = 0; sub < 4; sub++){
      int r = ty + 8 * sub;
      Wt[(size_t)(e0 + r) * 4096 + f0 + tx] = f2bf(ld[tx][r]);
    }
  } else {
    int r = bid - 2048;   // 0..271
    if (r < 256){
      for (int z = t; z < 288; z += 256)
        whzPh[(size_t)r * 288 + z] = (z < Z_) ? f2bf(whz[(size_t)r * Z_ + z]) : (unsigned short)0;
    }
    whzTPh[(size_t)r * 256 + t] = (r < Z_) ? f2bf(whz[(size_t)t * Z_ + r]) : (unsigned short)0;
  }
}

// ---------------- merged setup GEMMs (ata | pp) ----------------
__global__ __launch_bounds__(256) void k_gemms(const unsigned short* __restrict__ Wt,
    const unsigned short* __restrict__ imgb,
    float* __restrict__ ataPart, float* __restrict__ ppPart){
  int bid = blockIdx.x;
  int t = threadIdx.x, lane = t & 63, w = t >> 6, l15 = lane & 15, l4 = lane >> 4;
  if (bid < 256){
    int m0 = (bid & 15) * 16;
    size_t kc = (size_t)(bid >> 4) * 256;
    f32x4 acc[4];
#pragma unroll
    for (int q = 0; q < 4; q++) acc[q] = (f32x4){0.f, 0.f, 0.f, 0.f};
    for (int kt = 0; kt < 8; kt++){
      short8v a = *(const short8v*)&Wt[(size_t)(m0 + l15) * 4096 + kc + kt * 32 + l4 * 8];
#pragma unroll
      for (int q = 0; q < 4; q++){
        short8v b = *(const short8v*)&Wt[(size_t)(w * 64 + q * 16 + l15) * 4096 + kc + kt * 32 + l4 * 8];
        acc[q] = MFMA16(a, b, acc[q]);
      }
    }
    float* dst = ataPart + (size_t)(bid >> 4) * 65536;
#pragma unroll
    for (int q = 0; q < 4; q++)
#pragma unroll
      for (int j = 0; j < 4; j++)
        dst[(size_t)(m0 + l4 * 4 + j) * 256 + w * 64 + q * 16 + l15] = acc[q][j];
  } else {
    int idx = bid - 256;
    int m0 = (idx & 31) * 32;
    size_t kc = (size_t)(idx >> 5) * 512;
    f32x4 acc0[4], acc1[4];
#pragma unroll
    for (int q = 0; q < 4; q++){ acc0[q] = (f32x4){0.f,0.f,0.f,0.f}; acc1[q] = (f32x4){0.f,0.f,0.f,0.f}; }
    for (int kt = 0; kt < 16; kt++){
      short8v a0 = *(const short8v*)&imgb[(size_t)(m0 + l15) * 4096 + kc + kt * 32 + l4 * 8];
      short8v a1 = *(const short8v*)&imgb[(size_t)(m0 + 16 + l15) * 4096 + kc + kt * 32 + l4 * 8];
#pragma unroll
      for (int q = 0; q < 4; q++){
        short8v b = *(const short8v*)&Wt[(size_t)(w * 64 + q * 16 + l15) * 4096 + kc + kt * 32 + l4 * 8];
        acc0[q] = MFMA16(a0, b, acc0[q]);
        acc1[q] = MFMA16(a1, b, acc1[q]);
      }
    }
    float* dst = ppPart + (size_t)(idx >> 5) * (B_ * 256);
#pragma unroll
    for (int q = 0; q < 4; q++)
#pragma unroll
      for (int j = 0; j < 4; j++){
        dst[(size_t)(m0 + l4 * 4 + j) * 256 + w * 64 + q * 16 + l15] = acc0[q][j];
        dst[(size_t)(m0 + 16 + l4 * 4 + j) * 256 + w * 64 + q * 16 + l15] = acc1[q][j];
      }
  }
}

// ---------------- merged reductions ----------------
__global__ void k_reduce(const float* __restrict__ ataPart, unsigned short* __restrict__ Gh,
                         const float* __restrict__ ppPart, float* __restrict__ Pp){
  int bid = blockIdx.x, t = threadIdx.x;
  if (bid < 256){
    int i = bid * 256 + t;
    float s = 0.f;
#pragma unroll
    for (int p = 0; p < 16; p++) s += ataPart[(size_t)p * 65536 + i];
    Gh[i] = f2bf(s);
  } else {
    int i = (bid - 256) * 256 + t;
    float s = 0.f;
#pragma unroll
    for (int p = 0; p < 8; p++) s += ppPart[(size_t)p * (B_ * 256) + i];
    Pp[i] = s;
  }
}

// ---------------- fused 8-step inner loop (r5 verbatim: persistent reg weights,
// 66 us warm measured — best of 11 variants; spill traffic is cheaper than
// per-step weight re-streaming) ----------------
__global__ __launch_bounds__(512, 1) void k_inner(
    const unsigned short* __restrict__ whzPh,   // [256][288]
    const unsigned short* __restrict__ whzTPh,  // [272][256]
    const unsigned short* __restrict__ Gh,      // [256][256]
    const float* __restrict__ whzb,
    const float* __restrict__ blp,
    const float* __restrict__ Pp,
    const float* __restrict__ bso,
    float* __restrict__ nzOut, float* __restrict__ cA, float* __restrict__ rowB,
    uint32_t hk00, uint32_t hk01, uint32_t hk10, uint32_t hk11,
    uint32_t zk00, uint32_t zk01, uint32_t zk10, uint32_t zk11)
{
  __shared__ unsigned short zb[16][296];
  __shared__ unsigned short hbuf[2][16][296];
  __shared__ unsigned short sgb[16][296];
  __shared__ float zl[16][260];
  __shared__ float d2l[16][260];
  __shared__ float ppl[16][256];
  __shared__ float lsb[272];
  __shared__ float xbl[272];
  __shared__ float w256l[256];
  __shared__ uint64_t hbitL[272][2];
  __shared__ uint64_t zbitL[272][2];

  const int t = threadIdx.x;
  const int lane = t & 63;
  const int w = t >> 6;
  const int l15 = lane & 15;
  const int l4 = lane >> 4;
  const int blk = blockIdx.x;
  const int b0 = blk * 16;
  const int n0 = w * 32 + l15;
  const int n1 = n0 + 16;

  // ---- LDS init ----
  const unsigned short epsb = f2bf(EPS_);
  for (int i = t; i < 16 * 296; i += 512){
    int r = i / 296, c = i % 296;
    zb[r][c] = (c < Z_) ? epsb : (unsigned short)0;
    hbuf[0][r][c] = (c < 256) ? epsb : (unsigned short)0;
    hbuf[1][r][c] = 0;
    sgb[r][c] = 0;
  }
  for (int i = t; i < 16 * 260; i += 512){
    int r = i / 260, c = i % 260;
    zl[r][c] = (c < Z_) ? EPS_ : 0.f;
    d2l[r][c] = 0.f;
  }
  for (int i = t; i < 4096; i += 512)
    ppl[i >> 8][i & 255] = Pp[(size_t)(b0 + (i >> 8)) * 256 + (i & 255)];
  if (t < 272){
    float x = (t < Z_) ? blp[t] : 0.f;
    xbl[t] = x;
    lsb[t] = logsigf(x);
    hbitL[t][0] = tf64(hk00, hk01, (uint32_t)(blk * 272 + t));
    hbitL[t][1] = tf64(hk10, hk11, (uint32_t)(blk * 272 + t));
    zbitL[t][0] = tf64(zk00, zk01, (uint32_t)(blk * 272 + t));
    zbitL[t][1] = tf64(zk10, zk11, (uint32_t)(blk * 272 + t));
  }
  if (t < 256) w256l[t] = bf2f(whzTPh[(size_t)256 * 256 + t]);

  // ---- persistent register weights (192 VGPR intended; allocator spills some,
  // measured faster than streaming variants) ----
  short8v wA0[8], wA1[8], wB0[8], wB1[8], wC0[8], wC1[8];
#pragma unroll
  for (int kt = 0; kt < 8; kt++){
    wA0[kt] = *(const short8v*)&whzPh[(size_t)n0 * 288 + kt * 32 + l4 * 8];
    wA1[kt] = *(const short8v*)&whzPh[(size_t)n1 * 288 + kt * 32 + l4 * 8];
    wB0[kt] = *(const short8v*)&Gh[(size_t)n0 * 256 + kt * 32 + l4 * 8];
    wB1[kt] = *(const short8v*)&Gh[(size_t)n1 * 256 + kt * 32 + l4 * 8];
    wC0[kt] = *(const short8v*)&whzTPh[(size_t)n0 * 256 + kt * 32 + l4 * 8];
    wC1[kt] = *(const short8v*)&whzTPh[(size_t)n1 * 256 + kt * 32 + l4 * 8];
  }
  const float w256A0 = bf2f(whzPh[(size_t)n0 * 288 + 256]);
  const float w256A1 = bf2f(whzPh[(size_t)n1 * 288 + 256]);
  const float op = __expf(2.f * bso[0]);
  const float wbr0 = whzb[n0], wbr1 = whzb[n1];
  const float lsr0 = logsigf(blp[n0]), lsr1 = logsigf(blp[n1]);
  const float lsr2 = logsigf(blp[256]);
  float hreg0[4] = {EPS_, EPS_, EPS_, EPS_};
  float hreg1[4] = {EPS_, EPS_, EPS_, EPS_};
  __syncthreads();

  for (int s = 0; s < 8; s++){
    const int sg = s >> 2, sh = (s & 3) << 4;
    const int cur = s & 1, nx = cur ^ 1;

    // ---- phase A: hpl = z @ whz^T + b (z256 term scalar) ----
    f32x4 aA0 = {0.f, 0.f, 0.f, 0.f}, aA1 = {0.f, 0.f, 0.f, 0.f};
#pragma unroll
    for (int kt = 0; kt < 8; kt++){
      short8v zak = *(const short8v*)&zb[l15][kt * 32 + l4 * 8];
      aA0 = MFMA16(zak, wA0[kt], aA0);
      aA1 = MFMA16(zak, wA1[kt], aA1);
    }
#pragma unroll
    for (int j = 0; j < 4; j++){
      int m = l4 * 4 + j;
      float z256v = bf2f(zb[m][256]);
      float hpl0 = aA0[j] + wbr0 + z256v * w256A0;
      float hpl1 = aA1[j] + wbr1 + z256v * w256A1;
      d2l[m][n0] = logsigf(hpl0);
      d2l[m][n1] = logsigf(hpl1);
      sgb[m][n0] = f2bf(hreg0[j] * sigf(-hpl0));
      sgb[m][n1] = f2bf(hreg1[j] * sigf(-hpl1));
    }
    __syncthreads();   // S1: sgb/d2l complete

    // ---- phase B + C ----
    f32x4 aB0 = {0.f, 0.f, 0.f, 0.f}, aB1 = {0.f, 0.f, 0.f, 0.f};
    f32x4 aC0 = {0.f, 0.f, 0.f, 0.f}, aC1 = {0.f, 0.f, 0.f, 0.f};
#pragma unroll
    for (int kt = 0; kt < 8; kt++){
      short8v hak = *(const short8v*)&hbuf[cur][l15][kt * 32 + l4 * 8];
      short8v sak = *(const short8v*)&sgb[l15][kt * 32 + l4 * 8];
      aB0 = MFMA16(hak, wB0[kt], aB0);
      aB1 = MFMA16(hak, wB1[kt], aB1);
      aC0 = MFMA16(sak, wC0[kt], aC0);
      aC1 = MFMA16(sak, wC1[kt], aC1);
    }
    // wave 0: z[256] dot via VALU from sgb
    float zdot = 0.f;
    if (w == 0){
      int r = lane & 15, kg = lane >> 4;
#pragma unroll
      for (int c = 0; c < 8; c++){
        short8v sv = *(const short8v*)&sgb[r][kg * 64 + c * 8];
#pragma unroll
        for (int i = 0; i < 8; i++)
          zdot = fmaf(bf2f((unsigned short)sv[i]), w256l[kg * 64 + c * 8 + i], zdot);
      }
      zdot += __shfl_xor(zdot, 16);
      zdot += __shfl_xor(zdot, 32);
    }

    // h epilogue -> regs + hbuf[nx]
    {
      uint64_t hb0w = hbitL[n0][sg], hb1w = hbitL[n1][sg];
#pragma unroll
      for (int j = 0; j < 4; j++){
        int m = l4 * 4 + j;
        float hn0 = sigf(op * (ppl[m][n0] - aB0[j]) + d2l[m][n0]);
        float hn1 = sigf(op * (ppl[m][n1] - aB1[j]) + d2l[m][n1]);
        if ((hb0w >> (sh | m)) & 1ull) hreg0[j] = 0.5f * (hreg0[j] + hn0);
        if ((hb1w >> (sh | m)) & 1ull) hreg1[j] = 0.5f * (hreg1[j] + hn1);
        hbuf[nx][m][n0] = f2bf(hreg0[j]);
        hbuf[nx][m][n1] = f2bf(hreg1[j]);
      }
    }
    // z epilogue
    {
      uint64_t zb0w = zbitL[n0][sg], zb1w = zbitL[n1][sg];
#pragma unroll
      for (int j = 0; j < 4; j++){
        int m = l4 * 4 + j;
        float zx0 = sigf(aC0[j] + lsr0);
        float old0 = zl[m][n0];
        float nz0 = ((zb0w >> (sh | m)) & 1ull) ? 0.5f * (old0 + zx0) : old0;
        zl[m][n0] = nz0; zb[m][n0] = f2bf(nz0);
        float zx1 = sigf(aC1[j] + lsr1);
        float old1 = zl[m][n1];
        float nz1 = ((zb1w >> (sh | m)) & 1ull) ? 0.5f * (old1 + zx1) : old1;
        zl[m][n1] = nz1; zb[m][n1] = f2bf(nz1);
      }
    }
    if (w == 0 && lane < 16){
      int r = lane;
      uint64_t zw = zbitL[256][sg];
      float zx = sigf(zdot + lsr2);
      float old = zl[r][256];
      float nz = ((zw >> (sh | r)) & 1ull) ? 0.5f * (old + zx) : old;
      zl[r][256] = nz; zb[r][256] = f2bf(nz);
    }
    __syncthreads();   // S2
  }

  // ---- tail: nzOut + cA + rowB ----
  {
    int r = t >> 5, g = t & 31;
    float s = 0.f;
    for (int c = g; c < Z_; c += 32){
      float pz = zl[r][c];
      float lgp = __logf(pz);
      float lgq = log1pf(-pz);
      float x = xbl[c];
      nzOut[(size_t)(b0 + r) * Z_ + c] = pz;
      cA[(size_t)(b0 + r) * Z_ + c] = x - lgp + lgq;
      s += -(x - lsb[c]) - lgq;
    }
#pragma unroll
    for (int m = 16; m >= 1; m >>= 1) s += __shfl_xor(s, m);
    if (g == 0) rowB[b0 + r] = s;
  }
}

// ---------------- fused phase 2 (r15 verbatim: 16 rows/block, 1024 blocks) ----------------
__global__ __launch_bounds__(256) void k_phase2(
    const float* __restrict__ nzF, const float* __restrict__ cA,
    const float* __restrict__ rowBg,
    const unsigned short* __restrict__ whzPh, const float* __restrict__ whzb,
    const unsigned short* __restrict__ Gh, const float* __restrict__ Pp,
    const float* __restrict__ r2, const float* __restrict__ bso,
    float* __restrict__ joint,
    uint32_t zk0, uint32_t zk1, uint32_t hk0, uint32_t hk1){
  __shared__ unsigned short znl[16][296];
  __shared__ unsigned short hnl[16][264];
  __shared__ float lpl[16];
  __shared__ float sred[4][16][2];

  const int t = threadIdx.x, lane = t & 63, w = t >> 6;
  const int l15 = lane & 15, l4 = lane >> 4;
  const int m0 = blockIdx.x * 16;
  const int bb0 = m0 & (B_ - 1);

  for (int i = t; i < 16 * 32; i += 256)
    znl[i >> 5][256 + (i & 31)] = 0;

  {
    int rl = t >> 4, i = t & 15;
    int rg = m0 + rl;
    int b = bb0 + rl;
    float acc = 0.f;
#pragma unroll
    for (int k = 0; k < 8; k++){
      int tpos = i + 16 * k;
      uint32_t o0, o1;
      tf2x32(zk0, zk1, 0u, (uint32_t)(rg * 130 + tpos), &o0, &o1);
      int z0 = 2 * tpos;
      float pz0 = nzF[(size_t)b * Z_ + z0];
      float pz1 = nzF[(size_t)b * Z_ + z0 + 1];
      int v0 = u01(o0) < pz0;
      int v1 = u01(o1) < pz1;
      uint32_t pack = (v0 ? 0x3F80u : 0u) | (v1 ? 0x3F800000u : 0u);
      *(uint32_t*)&znl[rl][z0] = pack;
      if (v0) acc += cA[(size_t)b * Z_ + z0];
      if (v1) acc += cA[(size_t)b * Z_ + z0 + 1];
    }
#pragma unroll
    for (int msk = 1; msk < 16; msk <<= 1) acc += __shfl_xor(acc, msk);
    if (i == 0){
      uint32_t p0, p1;
      tf2x32(zk0, zk1, 0u, (uint32_t)(rg * 130 + 128), &p0, &p1);
      float pz = nzF[(size_t)b * Z_ + 256];
      int v = u01(p0) < pz;
      znl[rl][256] = v ? (unsigned short)0x3F80 : (unsigned short)0;
      if (v) acc += cA[(size_t)b * Z_ + 256];
      lpl[rl] = rowBg[b] + acc;
    }
  }
  __syncthreads();

  {
    short8v af[9];
#pragma unroll
    for (int kt = 0; kt < 9; kt++)
      af[kt] = *(const short8v*)&znl[l15][kt * 32 + l4 * 8];
#pragma unroll
    for (int q = 0; q < 4; q++){
      int n = w * 64 + q * 16 + l15;
      f32x4 acc = {0.f,0.f,0.f,0.f};
#pragma unroll
      for (int kt = 0; kt < 9; kt++){
        short8v bfr = *(const short8v*)&whzPh[(size_t)n * 288 + kt * 32 + l4 * 8];
        acc = MFMA16(af[kt], bfr, acc);
      }
      float wbv = whzb[n];
      int rbl = l4 * 4;
      int rbg = m0 + rbl;
      uint32_t c0 = (uint32_t)((rbg >> 1) * 256 + n);
      uint32_t ra0, rb0, ra1, rb1;
      tf2x32(hk0, hk1, 0u, c0, &ra0, &rb0);
      tf2x32(hk0, hk1, 0u, c0 + 256, &ra1, &rb1);
      float u[4] = {u01(ra0), u01(rb0), u01(ra1), u01(rb1)};
#pragma unroll
      for (int j = 0; j < 4; j++){
        float pr = sigf(acc[j] + wbv);
        hnl[rbl + j][n] = (u[j] < pr) ? (unsigned short)0x3F80 : (unsigned short)0;
      }
    }
  }
  __syncthreads();

  {
    short8v af[8];
#pragma unroll
    for (int kt = 0; kt < 8; kt++)
      af[kt] = *(const short8v*)&hnl[l15][kt * 32 + l4 * 8];
    float s1[4]={0.f,0.f,0.f,0.f}, s2[4]={0.f,0.f,0.f,0.f};
#pragma unroll
    for (int q = 0; q < 4; q++){
      int n = w * 64 + q * 16 + l15;
      f32x4 acc = {0.f,0.f,0.f,0.f};
#pragma unroll
      for (int kt = 0; kt < 8; kt++){
        short8v bfr = *(const short8v*)&Gh[(size_t)n * 256 + kt * 32 + l4 * 8];
        acc = MFMA16(af[kt], bfr, acc);
      }
#pragma unroll
      for (int j = 0; j < 4; j++){
        int gl = l4 * 4 + j;
        float hv = bf2f(hnl[gl][n]);
        float pp = Pp[(size_t)((m0 + gl) & (B_ - 1)) * 256 + n];
        s1[j] = fmaf(hv, acc[j], s1[j]);
        s2[j] = fmaf(hv, pp, s2[j]);
      }
    }
#pragma unroll
    for (int j = 0; j < 4; j++){
#pragma unroll
      for (int msk = 1; msk < 16; msk <<= 1){
        s1[j] += __shfl_xor(s1[j], msk);
        s2[j] += __shfl_xor(s2[j], msk);
      }
    }
    if (l15 == 0){
#pragma unroll
      for (int j = 0; j < 4; j++){
        sred[w][l4 * 4 + j][0] = s1[j];
        sred[w][l4 * 4 + j][1] = s2[j];
      }
    }
    __syncthreads();
    if (t < 16){
      float S1 = 0.f, S2 = 0.f;
#pragma unroll
      for (int wv = 0; wv < 4; wv++){ S1 += sred[wv][t][0]; S2 += sred[wv][t][1]; }
      int gm = m0 + t;
      int b = gm & (B_ - 1);
      float bs = bso[0];
      float isc2 = __expf(-2.f * bs);
      float se = r2[b] - 2.f * S2 + S1;
      joint[gm] = lpl[t] - 0.5f * isc2 * se - (float)FV_ * (bs + 0.91893853320467274f);
    }
  }
}

__global__ __launch_bounds__(1024) void k_final(const float* __restrict__ joint, float* __restrict__ out){
  int b = threadIdx.x;
  float mx = -3.0e38f;
  for (int n = 0; n < NS_; n++) mx = fmaxf(mx, joint[(size_t)n * B_ + b]);
  float s = 0.f;
  for (int n = 0; n < NS_; n++) s += __expf(joint[(size_t)n * B_ + b] - mx);
  float lse = mx + __logf(s) - 2.772588722239781f;
  __shared__ float red[1024];
  red[b] = lse; __syncthreads();
  for (int w = 512; w > 0; w >>= 1){ if (b < w) red[b] += red[b + w]; __syncthreads(); }
  if (!b) out[0] = -red[0] / (float)B_;
}

// ---------------- host ----------------
extern "C" void kernel_launch(void* const* d_in, const int* in_sizes, int n_in,
                              void* d_out, int out_size, void* d_ws, size_t ws_size,
                              hipStream_t stream){
  const float* img  = (const float*)d_in[0];
  const float* W    = (const float*)d_in[2];
  const float* wb   = (const float*)d_in[3];
  const float* whz  = (const float*)d_in[4];
  const float* whzb = (const float*)d_in[5];
  const float* blp  = (const float*)d_in[6];
  const float* bso  = (const float*)d_in[7];
  float* out = (float*)d_out;
  float* ws = (float*)d_ws;
  (void)in_sizes; (void)n_in; (void)out_size; (void)ws_size;

  size_t off = 0;
  auto nxt = [&](size_t n){ size_t o = off; off += (n + 63) & ~(size_t)63; return o; };
  float* Pp    = ws + nxt((size_t)B_ * 256);
  float* r2    = ws + nxt(B_);
  float* joint = ws + nxt(NSB_);
  float* nzF   = ws + nxt((size_t)B_ * Z_);
  float* cA    = ws + nxt((size_t)B_ * Z_);
  float* rowB  = ws + nxt(B_);
  unsigned short* Gh     = (unsigned short*)(ws + nxt((size_t)256 * 256 / 2));
  unsigned short* whzPh  = (unsigned short*)(ws + nxt((size_t)256 * 288 / 2));
  unsigned short* whzTPh = (unsigned short*)(ws + nxt((size_t)272 * 256 / 2));
  unsigned short* Wt     = (unsigned short*)(ws + nxt((size_t)256 * 4096 / 2));
  unsigned short* imgb   = (unsigned short*)(ws + nxt((size_t)B_ * FV_ / 2));
  float* ataPart = ws + nxt((size_t)16 * 65536);
  float* ppPart  = ws + nxt((size_t)8 * B_ * 256);

  uint32_t hk00, hk01, hk10, hk11, zk00, zk01, zk10, zk11;
  tf2x32(0u, 42u, 1u, 0u, &hk00, &hk01);
  tf2x32(0u, 42u, 1u, 1u, &hk10, &hk11);
  tf2x32(0u, 42u, 2u, 0u, &zk00, &zk01);
  tf2x32(0u, 42u, 2u, 1u, &zk10, &zk11);
  uint32_t sk00, sk01, sk10, sk11;
  tf2x32(0u, 7u, 0u, 0u, &sk00, &sk01);
  tf2x32(0u, 7u, 0u, 1u, &sk10, &sk11);

  k_prep<<<dim3(2320), 256, 0, stream>>>(img, wb, imgb, r2, W, Wt, whz, whzPh, whzTPh);
  k_gemms<<<dim3(512), 256, 0, stream>>>(Wt, imgb, ataPart, ppPart);
  k_reduce<<<dim3(1280), 256, 0, stream>>>(ataPart, Gh, ppPart, Pp);
  k_inner<<<dim3(64), 512, 0, stream>>>(whzPh, whzTPh, Gh, whzb, blp, Pp, bso,
                                        nzF, cA, rowB,
                                        hk00, hk01, hk10, hk11, zk00, zk01, zk10, zk11);
  k_phase2<<<dim3(1024), 256, 0, stream>>>(nzF, cA, rowB, whzPh, whzb, Gh, Pp, r2, bso,
                                           joint, sk00, sk01, sk10, sk11);
  k_final<<<dim3(1), 1024, 0, stream>>>(joint, out);
}